// Round 1
// 591.489 us; speedup vs baseline: 1.0367x; 1.0367x over previous
//
#include <hip/hip_runtime.h>
#include <hip/hip_bf16.h>

// Problem constants (from reference):
#define DIMV 2048   // dim
#define DIV  2048   // d_inner
#define BV   4
#define TV   4096
#define MV   (BV * TV)   // 16384 rows for both GEMMs
#define GK   2048        // K for both GEMMs
#define NCH  64          // scan chunks
#define CH   64          // scan chunk length (NCH*CH == TV)

typedef __bf16 bf16x8 __attribute__((ext_vector_type(8)));
typedef __bf16 bf16x4 __attribute__((ext_vector_type(4)));
typedef float  floatx4 __attribute__((ext_vector_type(4)));

__device__ __forceinline__ void gload_lds16(const void* g, void* l) {
    __builtin_amdgcn_global_load_lds((const __attribute__((address_space(1))) void*)g,
                                     (__attribute__((address_space(3))) void*)l,
                                     16, 0, 0);
}

// ---------------- fused fp32 -> bf16 conversion (x, W_in, W_out) ----------
__global__ __launch_bounds__(256) void cvt_all(const float4* __restrict__ x,
                                               const float4* __restrict__ wi,
                                               const float4* __restrict__ wo,
                                               ushort4* __restrict__ xb,
                                               ushort4* __restrict__ wib,
                                               ushort4* __restrict__ wob) {
    int i = blockIdx.x * 256 + threadIdx.x;
    const float4* src;
    ushort4* dst;
    int off;
    if (i < 8388608)       { src = x;  dst = xb;  off = 0; }
    else if (i < 9437184)  { src = wi; dst = wib; off = 8388608; }
    else                   { src = wo; dst = wob; off = 9437184; }
    float4 v = src[i - off];
    __hip_bfloat16 a = __float2bfloat16(v.x);
    __hip_bfloat16 b = __float2bfloat16(v.y);
    __hip_bfloat16 c = __float2bfloat16(v.z);
    __hip_bfloat16 d = __float2bfloat16(v.w);
    ushort4 o;
    o.x = *(unsigned short*)&a;
    o.y = *(unsigned short*)&b;
    o.z = *(unsigned short*)&c;
    o.w = *(unsigned short*)&d;
    dst[i - off] = o;
}

// ---------------- bf16 GEMM, B-transposed, 256x256 tile, deep pipeline ----
// C[m][n] = sum_k A[m][k] * Bt[n][k]; M=16384, N=2048, K=2048.
// 512 threads = 8 waves (2 M x 4 N); per wave 128x64 output = acc[8][4].
// LDS per matrix: [2 buf][2 panel][256 rows][32 cols] bf16 = 64 KiB (128 total).
// Panel p holds k-half p of the K=64 tile; row stride 64 B -> fragment b128
// reads spread over 8 x 16B slots (row parity x quad) = bank-minimal, and
// global_load_lds dest stays linear (wave-uniform base + lane*16).
// Pipeline: while computing tile t from buf (t&1), tile t+2 is staged into the
// same buf AFTER an lgkmcnt(0)+barrier (all waves' reads done). End-of-iter
// s_waitcnt vmcnt(8) keeps the newest 8 loads (tile t+2) in flight across the
// barrier — never vmcnt(0) in the main loop (T3+T4). setprio around MFMA (T5).
template <int EPI>
__global__ __launch_bounds__(512, 2) void gemm256_bt(const __hip_bfloat16* __restrict__ A,
                                                     const __hip_bfloat16* __restrict__ Bt,
                                                     float* __restrict__ Cf,
                                                     __hip_bfloat16* __restrict__ Cb) {
    __shared__ __align__(16) short As[32768];   // 2 buf x 16384 shorts = 64 KiB
    __shared__ __align__(16) short Bs[32768];

    const int tid  = threadIdx.x;
    const int lane = tid & 63;
    const int wave = tid >> 6;
    const int wm   = (wave >> 2) * 128;  // 2 wave-rows
    const int wn   = (wave & 3) * 64;    // 4 wave-cols
    const int lr   = lane & 15;
    const int lq   = lane >> 4;

    // T1: XCD-aware swizzle. 512 blocks, 8 XCDs -> each XCD owns an 8 m-tile
    // x 8 n-tile strip (n fastest) for L2 panel reuse. Bijective (512%8==0).
    const int p   = blockIdx.y * gridDim.x + blockIdx.x;   // dispatch-linear
    const int swz = (p & 7) * 64 + (p >> 3);
    const int m0  = (swz >> 3) * 256;
    const int n0  = (swz & 7) * 256;

    // Staging: 8 x global_load_lds(16B) per K-tile per matrix-pair.
    // Instr j: panel j&1, rows (j>>1)*128 .. +128; thread covers
    // row = r0 + tid/4, col = pan*32 + (tid&3)*8; LDS = uniform + tid*16B.
    const int trow = tid >> 2;
    const int tcol = (tid & 3) * 8;
    const __hip_bfloat16* aG = A  + (size_t)(m0 + trow) * GK + tcol;
    const __hip_bfloat16* bG = Bt + (size_t)(n0 + trow) * GK + tcol;
    short* aL = As + tid * 8;
    short* bL = Bs + tid * 8;

#define STAGE(T_, C_) do {                                                    \
    const size_t ko_ = (size_t)(T_) * 64;                                     \
    short* al_ = aL + (C_) * 16384;                                           \
    short* bl_ = bL + (C_) * 16384;                                           \
    gload_lds16(aG + ko_,                         al_);                       \
    gload_lds16(aG + ko_ + 32,                    al_ + 8192);                \
    gload_lds16(aG + ko_ + (size_t)128 * GK,      al_ + 4096);                \
    gload_lds16(aG + ko_ + (size_t)128 * GK + 32, al_ + 12288);               \
    gload_lds16(bG + ko_,                         bl_);                       \
    gload_lds16(bG + ko_ + 32,                    bl_ + 8192);                \
    gload_lds16(bG + ko_ + (size_t)128 * GK,      bl_ + 4096);                \
    gload_lds16(bG + ko_ + (size_t)128 * GK + 32, bl_ + 12288);               \
} while (0)

    floatx4 acc[8][4];
#pragma unroll
    for (int i = 0; i < 8; ++i)
#pragma unroll
        for (int j = 0; j < 4; ++j) acc[i][j] = 0.f;

    // Prologue: tiles 0,1 staged; wait tile 0 (8 newest stay in flight).
    STAGE(0, 0);
    STAGE(1, 1);
    asm volatile("s_waitcnt vmcnt(8)" ::: "memory");
    asm volatile("s_barrier" ::: "memory");

    const int aRd = (wm + lr) * 32 + lq * 8;   // short offsets
    const int bRd = (wn + lr) * 32 + lq * 8;

    // One K-tile (K=64): 24 ds_read_b128, 64 MFMA. Quadrant (mh=1,nh=1) runs
    // after the staging issue so loads overlap MFMA.
#define KSTEP(T_, DO_STAGE_, VM8_, VM0_) do {                                 \
    const int c_ = (T_) & 1;                                                  \
    const short* aP = As + c_ * 16384;                                        \
    const short* bP = Bs + c_ * 16384;                                        \
    bf16x8 afr[8][2], bfr[4][2];                                              \
    _Pragma("unroll") for (int s = 0; s < 2; ++s) {                           \
        _Pragma("unroll") for (int ni = 0; ni < 4; ++ni)                      \
            bfr[ni][s] = *(const bf16x8*)&bP[bRd + s * 8192 + ni * 512];      \
        _Pragma("unroll") for (int mi = 0; mi < 8; ++mi)                      \
            afr[mi][s] = *(const bf16x8*)&aP[aRd + s * 8192 + mi * 512];      \
    }                                                                         \
    __builtin_amdgcn_s_setprio(1);                                            \
    _Pragma("unroll") for (int mi = 0; mi < 4; ++mi)                          \
        _Pragma("unroll") for (int ni = 0; ni < 4; ++ni)                      \
            _Pragma("unroll") for (int s = 0; s < 2; ++s)                     \
                acc[mi][ni] = __builtin_amdgcn_mfma_f32_16x16x32_bf16(        \
                    afr[mi][s], bfr[ni][s], acc[mi][ni], 0, 0, 0);            \
    _Pragma("unroll") for (int mi = 4; mi < 8; ++mi)                          \
        _Pragma("unroll") for (int ni = 0; ni < 2; ++ni)                      \
            _Pragma("unroll") for (int s = 0; s < 2; ++s)                     \
                acc[mi][ni] = __builtin_amdgcn_mfma_f32_16x16x32_bf16(        \
                    afr[mi][s], bfr[ni][s], acc[mi][ni], 0, 0, 0);            \
    __builtin_amdgcn_s_setprio(0);                                            \
    /* all this wave's LDS reads complete before crossing (rule #18) */       \
    asm volatile("s_waitcnt lgkmcnt(0)" ::: "memory");                        \
    asm volatile("s_barrier" ::: "memory");                                   \
    if (DO_STAGE_) STAGE((T_) + 2, c_);                                       \
    __builtin_amdgcn_s_setprio(1);                                            \
    _Pragma("unroll") for (int mi = 4; mi < 8; ++mi)                          \
        _Pragma("unroll") for (int ni = 2; ni < 4; ++ni)                      \
            _Pragma("unroll") for (int s = 0; s < 2; ++s)                     \
                acc[mi][ni] = __builtin_amdgcn_mfma_f32_16x16x32_bf16(        \
                    afr[mi][s], bfr[ni][s], acc[mi][ni], 0, 0, 0);            \
    __builtin_amdgcn_s_setprio(0);                                            \
    if (VM8_) {                                                               \
        asm volatile("s_waitcnt vmcnt(8)" ::: "memory");                      \
        asm volatile("s_barrier" ::: "memory");                               \
    }                                                                         \
    if (VM0_) {                                                               \
        asm volatile("s_waitcnt vmcnt(0)" ::: "memory");                      \
        asm volatile("s_barrier" ::: "memory");                               \
    }                                                                         \
} while (0)

#pragma unroll 2
    for (int t = 0; t < 30; ++t) KSTEP(t, 1, 1, 0);
    KSTEP(30, 0, 0, 1);
    KSTEP(31, 0, 0, 0);

#undef KSTEP
#undef STAGE

    // Epilogue. C/D layout: col = lane&15, row = quad*4 + reg.
#pragma unroll
    for (int mi = 0; mi < 8; ++mi) {
#pragma unroll
        for (int r = 0; r < 4; ++r) {
            const int row = m0 + wm + mi * 16 + lq * 4 + r;
#pragma unroll
            for (int ni = 0; ni < 4; ++ni) {
                const int col = n0 + wn + ni * 16 + lr;
                float v = acc[mi][ni][r];
                if (EPI == 1) {
                    float s = v / (1.f + __expf(-v));   // silu
                    Cb[(size_t)row * DIV + col] = __float2bfloat16(s);
                } else {
                    Cf[(size_t)row * DIMV + col] = v;
                }
            }
        }
    }
}

// ---------------- scan pass 1: per-chunk carries (4 e-channels/thread) ----
__global__ __launch_bounds__(256) void scan_carry(const __hip_bfloat16* __restrict__ xp,
                                                  const float* __restrict__ logd,
                                                  const float* __restrict__ bias,
                                                  float* __restrict__ carry) {
    const int eg = blockIdx.x * 256 + threadIdx.x;  // e-group (4 channels)
    const int e0 = eg * 4;
    const int c = blockIdx.y;
    const int b = blockIdx.z;
    const float4 ld = ((const float4*)logd)[eg];
    const float4 bb = ((const float4*)bias)[eg];
    float dv[4] = {1.f / (1.f + __expf(-ld.x)), 1.f / (1.f + __expf(-ld.y)),
                   1.f / (1.f + __expf(-ld.z)), 1.f / (1.f + __expf(-ld.w))};
    float bv[4] = {bb.x, bb.y, bb.z, bb.w};
    const __hip_bfloat16* p = xp + ((size_t)(b * TV + c * CH)) * DIV + e0;
    float h[4] = {0.f, 0.f, 0.f, 0.f};
#pragma unroll 8
    for (int i = 0; i < CH; ++i) {
        bf16x4 v = *(const bf16x4*)(p + (size_t)i * DIV);
#pragma unroll
        for (int j = 0; j < 4; ++j)
            h[j] = dv[j] * ((float)v[j] + h[j]) + bv[j];
    }
    float4 o = {h[0], h[1], h[2], h[3]};
    *(float4*)&carry[((size_t)b * NCH + c) * DIV + e0] = o;
}

// ---------------- scan pass 2: combine carries, emit cell + h_final -------
__global__ __launch_bounds__(256) void scan_apply(const __hip_bfloat16* __restrict__ xp,
                                                  const float* __restrict__ logd,
                                                  const float* __restrict__ bias,
                                                  const float* __restrict__ h0,
                                                  const float* __restrict__ carry,
                                                  __hip_bfloat16* __restrict__ cell,
                                                  float* __restrict__ hfin) {
    const int eg = blockIdx.x * 256 + threadIdx.x;
    const int e0 = eg * 4;
    const int c = blockIdx.y;
    const int b = blockIdx.z;
    const float4 ld = ((const float4*)logd)[eg];
    const float4 bb = ((const float4*)bias)[eg];
    float dv[4] = {1.f / (1.f + __expf(-ld.x)), 1.f / (1.f + __expf(-ld.y)),
                   1.f / (1.f + __expf(-ld.z)), 1.f / (1.f + __expf(-ld.w))};
    float bv[4] = {bb.x, bb.y, bb.z, bb.w};
    float dCH[4];
#pragma unroll
    for (int j = 0; j < 4; ++j) dCH[j] = __powf(dv[j], (float)CH);

    // H = true h at entry to chunk c (chunk-level recurrence over carries)
    float4 H4 = *(const float4*)&h0[(size_t)b * DIV + e0];
    float H[4] = {H4.x, H4.y, H4.z, H4.w};
    for (int j = 0; j < c; ++j) {
        float4 cr = *(const float4*)&carry[((size_t)b * NCH + j) * DIV + e0];
#pragma unroll
        for (int q = 0; q < 4; ++q) H[q] = dCH[q] * H[q] + ((const float*)&cr)[q];
    }

    const size_t base = ((size_t)(b * TV + c * CH)) * DIV + e0;
    float h[4] = {H[0], H[1], H[2], H[3]};
#pragma unroll 4
    for (int i = 0; i < CH; ++i) {
        bf16x4 v = *(const bf16x4*)(xp + base + (size_t)i * DIV);
        ushort4 o;
        unsigned short* op = (unsigned short*)&o;
#pragma unroll
        for (int j = 0; j < 4; ++j) {
            h[j] = dv[j] * ((float)v[j] + h[j]) + bv[j];
            float cv = h[j] * (h[j] / (1.f + __expf(-h[j])));   // h * silu(h)
            __hip_bfloat16 cb = __float2bfloat16(cv);
            op[j] = *(unsigned short*)&cb;
        }
        *(ushort4*)(cell + base + (size_t)i * DIV) = o;
    }
    if (c == NCH - 1) {
        float4 o = {h[0], h[1], h[2], h[3]};
        *(float4*)&hfin[(size_t)b * DIV + e0] = o;
    }
}

// -------------------------------------------------------------------------
extern "C" void kernel_launch(void* const* d_in, const int* in_sizes, int n_in,
                              void* d_out, int out_size, void* d_ws, size_t ws_size,
                              hipStream_t stream) {
    const float* x     = (const float*)d_in[0];   // [B,T,DIM]
    const float* h0    = (const float*)d_in[1];   // [B,DI]
    const float* W_in  = (const float*)d_in[2];   // [DI,DIM]
    const float* W_out = (const float*)d_in[3];   // [DIM,DI]
    const float* log_d = (const float*)d_in[4];   // [DI]
    const float* bias  = (const float*)d_in[5];   // [DI]

    float* out  = (float*)d_out;                       // [B,T,DIM] fp32
    float* hfin = out + (size_t)BV * TV * DIMV;        // [B,DI] fp32

    // Workspace layout (bytes):
    char* ws = (char*)d_ws;
    __hip_bfloat16* xb    = (__hip_bfloat16*)ws;                          // 64 MiB
    __hip_bfloat16* cellb = xb;                                           // alias: x dead after GEMM1
    __hip_bfloat16* wib   = (__hip_bfloat16*)(ws + 67108864);             // 8 MiB
    __hip_bfloat16* wob   = (__hip_bfloat16*)(ws + 67108864 + 8388608);   // 8 MiB
    __hip_bfloat16* xpb   = (__hip_bfloat16*)(ws + 67108864 + 16777216);  // 64 MiB
    float*          carry = (float*)(ws + 134217728 + 16777216);          // 2 MiB

    // 1) convert inputs to bf16 (single fused kernel)
    {
        int n4 = 10485760;   // 8388608 + 1048576 + 1048576 float4s
        cvt_all<<<n4 / 256, 256, 0, stream>>>((const float4*)x, (const float4*)W_in,
                                              (const float4*)W_out,
                                              (ushort4*)xb, (ushort4*)wib, (ushort4*)wob);
    }

    // 2) GEMM1: xp = silu(x @ W_in^T), bf16 out
    gemm256_bt<1><<<dim3(DIV / 256, MV / 256), 512, 0, stream>>>(xb, wib, nullptr, xpb);

    // 3) scan: chunk carries, then combine + emit cell (bf16) and h_final
    scan_carry<<<dim3(DIV / 1024, NCH, BV), 256, 0, stream>>>(xpb, log_d, bias, carry);
    scan_apply<<<dim3(DIV / 1024, NCH, BV), 256, 0, stream>>>(xpb, log_d, bias, h0, carry, cellb, hfin);

    // 4) GEMM2: out = cell @ W_out^T, fp32 out
    gemm256_bt<0><<<dim3(DIMV / 256, MV / 256), 512, 0, stream>>>(cellb, wob, out, nullptr);
}

// Round 2
// 590.833 us; speedup vs baseline: 1.0378x; 1.0011x over previous
//
#include <hip/hip_runtime.h>
#include <hip/hip_bf16.h>

// Problem constants (from reference):
#define DIMV 2048   // dim
#define DIV  2048   // d_inner
#define BV   4
#define TV   4096
#define MV   (BV * TV)   // 16384 rows for both GEMMs
#define GK   2048        // K for both GEMMs
#define NCH  64          // scan chunks
#define CH   64          // scan chunk length (NCH*CH == TV)

typedef __bf16 bf16x8 __attribute__((ext_vector_type(8)));
typedef __bf16 bf16x4 __attribute__((ext_vector_type(4)));
typedef float  floatx4 __attribute__((ext_vector_type(4)));

__device__ __forceinline__ void gload_lds16(const void* g, void* l) {
    __builtin_amdgcn_global_load_lds((const __attribute__((address_space(1))) void*)g,
                                     (__attribute__((address_space(3))) void*)l,
                                     16, 0, 0);
}

// ---------------- fused fp32 -> bf16 conversion (x, W_in, W_out) ----------
__global__ __launch_bounds__(256) void cvt_all(const float4* __restrict__ x,
                                               const float4* __restrict__ wi,
                                               const float4* __restrict__ wo,
                                               ushort4* __restrict__ xb,
                                               ushort4* __restrict__ wib,
                                               ushort4* __restrict__ wob) {
    int i = blockIdx.x * 256 + threadIdx.x;
    const float4* src;
    ushort4* dst;
    int off;
    if (i < 8388608)       { src = x;  dst = xb;  off = 0; }
    else if (i < 9437184)  { src = wi; dst = wib; off = 8388608; }
    else                   { src = wo; dst = wob; off = 9437184; }
    float4 v = src[i - off];
    __hip_bfloat16 a = __float2bfloat16(v.x);
    __hip_bfloat16 b = __float2bfloat16(v.y);
    __hip_bfloat16 c = __float2bfloat16(v.z);
    __hip_bfloat16 d = __float2bfloat16(v.w);
    ushort4 o;
    o.x = *(unsigned short*)&a;
    o.y = *(unsigned short*)&b;
    o.z = *(unsigned short*)&c;
    o.w = *(unsigned short*)&d;
    dst[i - off] = o;
}

// ---------------- bf16 GEMM, B-transposed, 256x256 tile, 8-phase schedule -
// C[m][n] = sum_k A[m][k] * Bt[n][k]; M=16384, N=2048, K=2048.
// 512 threads = 8 waves (2 M x 4 N); per wave 128x64 output = acc[8][4].
// LDS per matrix: [2 buf][2 half][128 rows][64 cols] bf16 = 64 KiB (128 tot).
// T2 swizzle: byte-within-half ^= ((byte>>9)&1)<<5 on ds_read addrs; the
// global SOURCE of each global_load_lds lane is inverse-permuted so the
// linear LDS dest (uniform + tid*16) receives swizzled-home data (rule #21).
// Per K-tile: 4 phases, each {ds_read quadrant frags | 2 stage loads ->
// barrier -> lgkmcnt(0)+sched_barrier -> setprio(1) 16 MFMA setprio(0) ->
// counted vmcnt -> barrier}. Stage of tile t+2 staggered into the buffer
// being read: region overwritten only the phase AFTER its last read retired
// (safe via the 2-barriers/phase structure). vmcnt never drains to 0 (T4).
template <int EPI>
__global__ __launch_bounds__(512, 2) void gemm256_bt(const __hip_bfloat16* __restrict__ A,
                                                     const __hip_bfloat16* __restrict__ Bt,
                                                     float* __restrict__ Cf,
                                                     __hip_bfloat16* __restrict__ Cb) {
    __shared__ __align__(16) char AsB[65536];   // 2 buf x 2 half x 16 KiB
    __shared__ __align__(16) char BsB[65536];

    const int tid  = threadIdx.x;
    const int lane = tid & 63;
    const int wave = tid >> 6;
    const int wmh  = wave >> 2;          // A half (0/1); wm = wmh*128
    const int wnh  = (wave >> 1) & 1;    // B half
    const int wno  = wave & 1;           // 64-row block within B half
    const int lr   = lane & 15;
    const int lq   = lane >> 4;

    // T1: XCD-aware swizzle. 512 blocks, 8 XCDs, bijective (512 % 8 == 0).
    const int p   = blockIdx.y * gridDim.x + blockIdx.x;
    const int swz = (p & 7) * 64 + (p >> 3);
    const int m0  = (swz >> 3) * 256;
    const int n0  = (swz & 7) * 256;

    // Swizzled fragment-read base (byte offset within a 16 KiB half-tile):
    // logical byte L = mi*2048 + lr*128 + s*64 + lq*16; bit9 of L = lr bit2.
    const int flip  = ((lr >> 2) & 1) << 5;
    const int rdswz = lr * 128 + ((lq * 16) ^ flip);
    const char* aRd0 = AsB + wmh * 16384 + rdswz;
    const char* bRd0 = BsB + wnh * 16384 + wno * 8192 + rdswz;

    // Staging source (pre-swizzled global): dest byte D = g*8192 + tid*16
    // holds logical P = S(D): ptid = tid ^ ((tid>>5&1)<<1).
    const int ptid = tid ^ (((tid >> 5) & 1) << 1);
    const int srow = ptid >> 3;          // row within 64-row seg
    const int scol = (ptid & 7) * 8;     // col (bf16) within 64-col K-tile
    const __hip_bfloat16* aS_h0g0 = A  + (size_t)(m0 +   0 +  0 + srow) * GK + scol;
    const __hip_bfloat16* aS_h0g1 = A  + (size_t)(m0 +   0 + 64 + srow) * GK + scol;
    const __hip_bfloat16* aS_h1g0 = A  + (size_t)(m0 + 128 +  0 + srow) * GK + scol;
    const __hip_bfloat16* aS_h1g1 = A  + (size_t)(m0 + 128 + 64 + srow) * GK + scol;
    const __hip_bfloat16* bS_h0g0 = Bt + (size_t)(n0 +   0 +  0 + srow) * GK + scol;
    const __hip_bfloat16* bS_h0g1 = Bt + (size_t)(n0 +   0 + 64 + srow) * GK + scol;
    const __hip_bfloat16* bS_h1g0 = Bt + (size_t)(n0 + 128 +  0 + srow) * GK + scol;
    const __hip_bfloat16* bS_h1g1 = Bt + (size_t)(n0 + 128 + 64 + srow) * GK + scol;

#define BARR  asm volatile("s_barrier" ::: "memory")
#define WAITL do { asm volatile("s_waitcnt lgkmcnt(0)" ::: "memory");          \
                   __builtin_amdgcn_sched_barrier(0); } while (0)
#define VMW(N_) asm volatile("s_waitcnt vmcnt(" #N_ ")" ::: "memory")

#define STG(SRC_, DST_, T_) gload_lds16((SRC_) + (size_t)(T_) * 64, (DST_))
#define ST_AG0(T_, C_) do {                                                    \
    STG(aS_h0g0, AsB + (C_) * 32768 +     0 + tid * 16, T_);                   \
    STG(aS_h1g0, AsB + (C_) * 32768 + 16384 + tid * 16, T_); } while (0)
#define ST_AG1(T_, C_) do {                                                    \
    STG(aS_h0g1, AsB + (C_) * 32768 +  8192 + tid * 16, T_);                   \
    STG(aS_h1g1, AsB + (C_) * 32768 + 24576 + tid * 16, T_); } while (0)
#define ST_BG0(T_, C_) do {                                                    \
    STG(bS_h0g0, BsB + (C_) * 32768 +     0 + tid * 16, T_);                   \
    STG(bS_h1g0, BsB + (C_) * 32768 + 16384 + tid * 16, T_); } while (0)
#define ST_BG1(T_, C_) do {                                                    \
    STG(bS_h0g1, BsB + (C_) * 32768 +  8192 + tid * 16, T_);                   \
    STG(bS_h1g1, BsB + (C_) * 32768 + 24576 + tid * 16, T_); } while (0)

#define RDPH_A(DST_, MI0_, C_)                                                 \
    _Pragma("unroll") for (int mi_ = 0; mi_ < 4; ++mi_)                        \
      _Pragma("unroll") for (int s_ = 0; s_ < 2; ++s_)                         \
        DST_[mi_][s_] = *(const bf16x8*)(aRd0 + (C_) * 32768 +                 \
                                         ((MI0_) + mi_) * 2048 + s_ * 64);
#define RDPH_B(DST_, NI0_, C_)                                                 \
    _Pragma("unroll") for (int ni_ = 0; ni_ < 2; ++ni_)                        \
      _Pragma("unroll") for (int s_ = 0; s_ < 2; ++s_)                         \
        DST_[ni_][s_] = *(const bf16x8*)(bRd0 + (C_) * 32768 +                 \
                                         ((NI0_) + ni_) * 2048 + s_ * 64);

#define QUAD(MI0_, NI0_, AF_, BF_)                                             \
    __builtin_amdgcn_s_setprio(1);                                             \
    _Pragma("unroll") for (int mi_ = 0; mi_ < 4; ++mi_)                        \
      _Pragma("unroll") for (int ni_ = 0; ni_ < 2; ++ni_)                      \
        _Pragma("unroll") for (int s_ = 0; s_ < 2; ++s_)                       \
          acc[(MI0_) + mi_][(NI0_) + ni_] =                                    \
            __builtin_amdgcn_mfma_f32_16x16x32_bf16(                           \
              AF_[mi_][s_], BF_[ni_][s_],                                      \
              acc[(MI0_) + mi_][(NI0_) + ni_], 0, 0, 0);                       \
    __builtin_amdgcn_s_setprio(0);

// One K-tile = 4 phases. Quadrant order (reg reuse, 24 ds_read/K-tile):
//   ph0: read a03,b01 (12) -> Q(mi0-3,ni0-1);  stage BG1(t+1) into buf^1
//   ph1: read b23 (4)      -> Q(mi0-3,ni2-3);  stage AG0(t+2) into buf
//   ph2: read a47 (8)      -> Q(mi4-7,ni2-3);  stage BG0(t+2) into buf
//   ph3: (held regs)       -> Q(mi4-7,ni0-1);  stage AG1(t+2) into buf
// Counted waits (derived from 4-phase issue->consume distance):
//   ph0 end vmcnt(8); ph1 end vmcnt(4); ph2 end none; ph3 end vmcnt(6)
//   (MODE 2: last staged tile -> ph3 drains vmcnt(0)).
#define KTILE(T_, C_, MODE_) do {                                              \
    bf16x8 a03[4][2], a47[4][2], b01[2][2], b23[2][2];                         \
    /* ---- phase 0 ---- */                                                    \
    RDPH_A(a03, 0, C_);                                                        \
    RDPH_B(b01, 0, C_);                                                        \
    if ((MODE_) >= 1) { ST_BG1((T_) + 1, (C_) ^ 1); }                          \
    BARR; WAITL;                                                               \
    QUAD(0, 0, a03, b01);                                                      \
    VMW(8); BARR;                                                              \
    /* ---- phase 1 ---- */                                                    \
    RDPH_B(b23, 2, C_);                                                        \
    if ((MODE_) == 1) { ST_AG0((T_) + 2, C_); }                                \
    BARR; WAITL;                                                               \
    QUAD(0, 2, a03, b23);                                                      \
    VMW(4); BARR;                                                              \
    /* ---- phase 2 ---- */                                                    \
    RDPH_A(a47, 4, C_);                                                        \
    if ((MODE_) == 1) { ST_BG0((T_) + 2, C_); }                                \
    BARR; WAITL;                                                               \
    QUAD(4, 2, a47, b23);                                                      \
    BARR;                                                                      \
    /* ---- phase 3 ---- */                                                    \
    if ((MODE_) == 1) { ST_AG1((T_) + 2, C_); }                                \
    BARR;                                                                      \
    QUAD(4, 0, a47, b01);                                                      \
    if ((MODE_) == 2) { VMW(0); } else { VMW(6); }                             \
    BARR;                                                                      \
} while (0)

    floatx4 acc[8][4];
#pragma unroll
    for (int i = 0; i < 8; ++i)
#pragma unroll
        for (int j = 0; j < 4; ++j) acc[i][j] = 0.f;

    // Prologue: tile 0 fully + tile 1 (AG0,BG0,AG1); BG1(1) comes at t0.ph0.
    // vmcnt(6) leaves tile-1's 3 pairs in flight, tile 0 fully landed.
    ST_AG0(0, 0); ST_BG0(0, 0); ST_AG1(0, 0); ST_BG1(0, 0);
    ST_AG0(1, 1); ST_BG0(1, 1); ST_AG1(1, 1);
    VMW(6); BARR;

    for (int t2 = 0; t2 < 15; ++t2) {        // tiles 0..29
        KTILE(2 * t2,     0, 1);
        KTILE(2 * t2 + 1, 1, 1);
    }
    KTILE(30, 0, 2);                          // stages BG1(31) only; drains
    KTILE(31, 1, 0);                          // no staging

#undef KTILE
#undef QUAD
#undef RDPH_A
#undef RDPH_B
#undef ST_AG0
#undef ST_AG1
#undef ST_BG0
#undef ST_BG1
#undef STG
#undef VMW
#undef WAITL
#undef BARR

    // Epilogue. C/D layout: col = lane&15, row = quad*4 + reg.
    const int wm = wmh * 128;
    const int wn = (wave & 3) * 64;
#pragma unroll
    for (int mi = 0; mi < 8; ++mi) {
#pragma unroll
        for (int r = 0; r < 4; ++r) {
            const int row = m0 + wm + mi * 16 + lq * 4 + r;
#pragma unroll
            for (int ni = 0; ni < 4; ++ni) {
                const int col = n0 + wn + ni * 16 + lr;
                float v = acc[mi][ni][r];
                if (EPI == 1) {
                    float s = v / (1.f + __expf(-v));   // silu
                    Cb[(size_t)row * DIV + col] = __float2bfloat16(s);
                } else {
                    Cf[(size_t)row * DIMV + col] = v;
                }
            }
        }
    }
}

// ---------------- scan pass 1: per-chunk carries (4 e-channels/thread) ----
__global__ __launch_bounds__(256) void scan_carry(const __hip_bfloat16* __restrict__ xp,
                                                  const float* __restrict__ logd,
                                                  const float* __restrict__ bias,
                                                  float* __restrict__ carry) {
    const int eg = blockIdx.x * 256 + threadIdx.x;  // e-group (4 channels)
    const int e0 = eg * 4;
    const int c = blockIdx.y;
    const int b = blockIdx.z;
    const float4 ld = ((const float4*)logd)[eg];
    const float4 bb = ((const float4*)bias)[eg];
    float dv[4] = {1.f / (1.f + __expf(-ld.x)), 1.f / (1.f + __expf(-ld.y)),
                   1.f / (1.f + __expf(-ld.z)), 1.f / (1.f + __expf(-ld.w))};
    float bv[4] = {bb.x, bb.y, bb.z, bb.w};
    const __hip_bfloat16* p = xp + ((size_t)(b * TV + c * CH)) * DIV + e0;
    float h[4] = {0.f, 0.f, 0.f, 0.f};
#pragma unroll 8
    for (int i = 0; i < CH; ++i) {
        bf16x4 v = *(const bf16x4*)(p + (size_t)i * DIV);
#pragma unroll
        for (int j = 0; j < 4; ++j)
            h[j] = dv[j] * ((float)v[j] + h[j]) + bv[j];
    }
    float4 o = {h[0], h[1], h[2], h[3]};
    *(float4*)&carry[((size_t)b * NCH + c) * DIV + e0] = o;
}

// ---------------- scan pass 2: combine carries, emit cell + h_final -------
__global__ __launch_bounds__(256) void scan_apply(const __hip_bfloat16* __restrict__ xp,
                                                  const float* __restrict__ logd,
                                                  const float* __restrict__ bias,
                                                  const float* __restrict__ h0,
                                                  const float* __restrict__ carry,
                                                  __hip_bfloat16* __restrict__ cell,
                                                  float* __restrict__ hfin) {
    const int eg = blockIdx.x * 256 + threadIdx.x;
    const int e0 = eg * 4;
    const int c = blockIdx.y;
    const int b = blockIdx.z;
    const float4 ld = ((const float4*)logd)[eg];
    const float4 bb = ((const float4*)bias)[eg];
    float dv[4] = {1.f / (1.f + __expf(-ld.x)), 1.f / (1.f + __expf(-ld.y)),
                   1.f / (1.f + __expf(-ld.z)), 1.f / (1.f + __expf(-ld.w))};
    float bv[4] = {bb.x, bb.y, bb.z, bb.w};
    float dCH[4];
#pragma unroll
    for (int j = 0; j < 4; ++j) dCH[j] = __powf(dv[j], (float)CH);

    // H = true h at entry to chunk c (chunk-level recurrence over carries)
    float4 H4 = *(const float4*)&h0[(size_t)b * DIV + e0];
    float H[4] = {H4.x, H4.y, H4.z, H4.w};
    for (int j = 0; j < c; ++j) {
        float4 cr = *(const float4*)&carry[((size_t)b * NCH + j) * DIV + e0];
#pragma unroll
        for (int q = 0; q < 4; ++q) H[q] = dCH[q] * H[q] + ((const float*)&cr)[q];
    }

    const size_t base = ((size_t)(b * TV + c * CH)) * DIV + e0;
    float h[4] = {H[0], H[1], H[2], H[3]};
#pragma unroll 4
    for (int i = 0; i < CH; ++i) {
        bf16x4 v = *(const bf16x4*)(xp + base + (size_t)i * DIV);
        ushort4 o;
        unsigned short* op = (unsigned short*)&o;
#pragma unroll
        for (int j = 0; j < 4; ++j) {
            h[j] = dv[j] * ((float)v[j] + h[j]) + bv[j];
            float cv = h[j] * (h[j] / (1.f + __expf(-h[j])));   // h * silu(h)
            __hip_bfloat16 cb = __float2bfloat16(cv);
            op[j] = *(unsigned short*)&cb;
        }
        *(ushort4*)(cell + base + (size_t)i * DIV) = o;
    }
    if (c == NCH - 1) {
        float4 o = {h[0], h[1], h[2], h[3]};
        *(float4*)&hfin[(size_t)b * DIV + e0] = o;
    }
}

// -------------------------------------------------------------------------
extern "C" void kernel_launch(void* const* d_in, const int* in_sizes, int n_in,
                              void* d_out, int out_size, void* d_ws, size_t ws_size,
                              hipStream_t stream) {
    const float* x     = (const float*)d_in[0];   // [B,T,DIM]
    const float* h0    = (const float*)d_in[1];   // [B,DI]
    const float* W_in  = (const float*)d_in[2];   // [DI,DIM]
    const float* W_out = (const float*)d_in[3];   // [DIM,DI]
    const float* log_d = (const float*)d_in[4];   // [DI]
    const float* bias  = (const float*)d_in[5];   // [DI]

    float* out  = (float*)d_out;                       // [B,T,DIM] fp32
    float* hfin = out + (size_t)BV * TV * DIMV;        // [B,DI] fp32

    // Workspace layout (bytes):
    char* ws = (char*)d_ws;
    __hip_bfloat16* xb    = (__hip_bfloat16*)ws;                          // 64 MiB
    __hip_bfloat16* cellb = xb;                                           // alias: x dead after GEMM1
    __hip_bfloat16* wib   = (__hip_bfloat16*)(ws + 67108864);             // 8 MiB
    __hip_bfloat16* wob   = (__hip_bfloat16*)(ws + 67108864 + 8388608);   // 8 MiB
    __hip_bfloat16* xpb   = (__hip_bfloat16*)(ws + 67108864 + 16777216);  // 64 MiB
    float*          carry = (float*)(ws + 134217728 + 16777216);          // 2 MiB

    // 1) convert inputs to bf16 (single fused kernel)
    {
        int n4 = 10485760;   // 8388608 + 1048576 + 1048576 float4s
        cvt_all<<<n4 / 256, 256, 0, stream>>>((const float4*)x, (const float4*)W_in,
                                              (const float4*)W_out,
                                              (ushort4*)xb, (ushort4*)wib, (ushort4*)wob);
    }

    // 2) GEMM1: xp = silu(x @ W_in^T), bf16 out
    gemm256_bt<1><<<dim3(DIV / 256, MV / 256), 512, 0, stream>>>(xb, wib, nullptr, xpb);

    // 3) scan: chunk carries, then combine + emit cell (bf16) and h_final
    scan_carry<<<dim3(DIV / 1024, NCH, BV), 256, 0, stream>>>(xpb, log_d, bias, carry);
    scan_apply<<<dim3(DIV / 1024, NCH, BV), 256, 0, stream>>>(xpb, log_d, bias, h0, carry, cellb, hfin);

    // 4) GEMM2: out = cell @ W_out^T, fp32 out
    gemm256_bt<0><<<dim3(DIMV / 256, MV / 256), 512, 0, stream>>>(cellb, wob, out, nullptr);
}

// Round 3
// 559.010 us; speedup vs baseline: 1.0969x; 1.0569x over previous
//
#include <hip/hip_runtime.h>
#include <hip/hip_bf16.h>

// Problem constants (from reference):
#define DIMV 2048   // dim
#define DIV  2048   // d_inner
#define BV   4
#define TV   4096
#define MV   (BV * TV)   // 16384 rows for both GEMMs
#define GK   2048        // K for both GEMMs
#define NCH  64          // scan chunks
#define CH   64          // scan chunk length (NCH*CH == TV)

typedef __bf16 bf16x8 __attribute__((ext_vector_type(8)));
typedef __bf16 bf16x4 __attribute__((ext_vector_type(4)));
typedef float  floatx4 __attribute__((ext_vector_type(4)));

__device__ __forceinline__ void gload_lds16(const void* g, void* l) {
    __builtin_amdgcn_global_load_lds((const __attribute__((address_space(1))) void*)g,
                                     (__attribute__((address_space(3))) void*)l,
                                     16, 0, 0);
}

// ---------------- fused fp32 -> bf16 conversion (x, W_in, W_out) ----------
__global__ __launch_bounds__(256) void cvt_all(const float4* __restrict__ x,
                                               const float4* __restrict__ wi,
                                               const float4* __restrict__ wo,
                                               ushort4* __restrict__ xb,
                                               ushort4* __restrict__ wib,
                                               ushort4* __restrict__ wob) {
    int i = blockIdx.x * 256 + threadIdx.x;
    const float4* src;
    ushort4* dst;
    int off;
    if (i < 8388608)       { src = x;  dst = xb;  off = 0; }
    else if (i < 9437184)  { src = wi; dst = wib; off = 8388608; }
    else                   { src = wo; dst = wob; off = 9437184; }
    float4 v = src[i - off];
    __hip_bfloat16 a = __float2bfloat16(v.x);
    __hip_bfloat16 b = __float2bfloat16(v.y);
    __hip_bfloat16 c = __float2bfloat16(v.z);
    __hip_bfloat16 d = __float2bfloat16(v.w);
    ushort4 o;
    o.x = *(unsigned short*)&a;
    o.y = *(unsigned short*)&b;
    o.z = *(unsigned short*)&c;
    o.w = *(unsigned short*)&d;
    dst[i - off] = o;
}

// ---------------- bf16 GEMM, B-transposed, 256x256 tile, 8-phase schedule -
// C[m][n] = sum_k A[m][k] * Bt[n][k]; M=16384, N=2048, K=2048.
// 512 threads = 8 waves (2 M x 4 N); per wave 128x64 output = acc[8][4].
// LDS per matrix: [2 buf][2 half][128 rows][64 cols] bf16 = 64 KiB (128 tot).
// T2 swizzle (full 3-bit): phys = row*128 + (col_byte ^ ((row&7)<<4)).
// For any 16-consecutive-lane group (fixed lq), lr=0..15 covers all 8
// 16-B slots of a 128-B row exactly twice -> 2-way = free. The global
// SOURCE column of each global_load_lds lane is inverse-permuted
// (scol = ((tid&7)^(row&7))*8) so the linear LDS dest (uniform + tid*16)
// receives swizzled-home data (rule #21: both sides or neither).
// Pipeline: per K-tile 4 phases x {ds_read | stage -> barrier -> lgkmcnt(0)
// + sched_barrier -> setprio(1) 16 MFMA setprio(0) -> barrier}. Tile t+2 is
// staged into the buffer being read, at the phase AFTER each region's last
// read retired (all waves' lgkmcnt(0) precede the phase-end barrier).
// ONE counted vmcnt per K-tile (end of ph3): vmcnt(8) keeps tile t+2's 8
// loads in flight; waits only on loads issued a full tile earlier (T3+T4).
template <int EPI>
__global__ __launch_bounds__(512, 2) void gemm256_bt(const __hip_bfloat16* __restrict__ A,
                                                     const __hip_bfloat16* __restrict__ Bt,
                                                     float* __restrict__ Cf,
                                                     __hip_bfloat16* __restrict__ Cb) {
    __shared__ __align__(16) char AsB[65536];   // 2 buf x 2 half x 16 KiB
    __shared__ __align__(16) char BsB[65536];

    const int tid  = threadIdx.x;
    const int lane = tid & 63;
    const int wave = tid >> 6;
    const int wmh  = wave >> 2;          // A half (0/1); wm = wmh*128
    const int wnh  = (wave >> 1) & 1;    // B half
    const int wno  = wave & 1;           // 64-row block within B half
    const int lr   = lane & 15;
    const int lq   = lane >> 4;

    // T1: XCD-aware swizzle. 512 blocks, 8 XCDs, bijective (512 % 8 == 0).
    const int p   = blockIdx.y * gridDim.x + blockIdx.x;
    const int swz = (p & 7) * 64 + (p >> 3);
    const int m0  = (swz >> 3) * 256;
    const int n0  = (swz & 7) * 256;

    // Swizzled fragment-read offsets within a 16 KiB half-tile:
    // logical (row = mi*16+lr, col_byte = s*64 + lq*16); row&7 == lr&7.
    // phys = mi*2048 + lr*128 + ((s*64 + lq*16) ^ ((lr&7)<<4)).
    const int rdswz = lr * 128 + ((lq * 16) ^ ((lr & 7) << 4));
    const int rds[2] = { rdswz, rdswz ^ 64 };     // s=0 / s=1 (bit6 flip)
    const char* aRd0 = AsB + wmh * 16384;
    const char* bRd0 = BsB + wnh * 16384 + wno * 8192;

    // Staging source (inverse-swizzled global column): dest byte D = tid*16
    // within an 8192-B segment covers row = tid>>3, phys-in-row (tid&7)*16;
    // the logical data that belongs there is col ((tid&7)^(row&7))*16 B.
    const int srow = tid >> 3;                       // row within 64-row seg
    const int scol = ((tid & 7) ^ (srow & 7)) * 8;   // bf16 col within K-tile
    const __hip_bfloat16* aS_h0g0 = A  + (size_t)(m0 +   0 +  0 + srow) * GK + scol;
    const __hip_bfloat16* aS_h0g1 = A  + (size_t)(m0 +   0 + 64 + srow) * GK + scol;
    const __hip_bfloat16* aS_h1g0 = A  + (size_t)(m0 + 128 +  0 + srow) * GK + scol;
    const __hip_bfloat16* aS_h1g1 = A  + (size_t)(m0 + 128 + 64 + srow) * GK + scol;
    const __hip_bfloat16* bS_h0g0 = Bt + (size_t)(n0 +   0 +  0 + srow) * GK + scol;
    const __hip_bfloat16* bS_h0g1 = Bt + (size_t)(n0 +   0 + 64 + srow) * GK + scol;
    const __hip_bfloat16* bS_h1g0 = Bt + (size_t)(n0 + 128 +  0 + srow) * GK + scol;
    const __hip_bfloat16* bS_h1g1 = Bt + (size_t)(n0 + 128 + 64 + srow) * GK + scol;

#define BARR  asm volatile("s_barrier" ::: "memory")
#define WAITL do { asm volatile("s_waitcnt lgkmcnt(0)" ::: "memory");          \
                   __builtin_amdgcn_sched_barrier(0); } while (0)
#define VMW(N_) asm volatile("s_waitcnt vmcnt(" #N_ ")" ::: "memory")

#define STG(SRC_, DST_, T_) gload_lds16((SRC_) + (size_t)(T_) * 64, (DST_))
#define ST_AG0(T_, C_) do {                                                    \
    STG(aS_h0g0, AsB + (C_) * 32768 +     0 + tid * 16, T_);                   \
    STG(aS_h1g0, AsB + (C_) * 32768 + 16384 + tid * 16, T_); } while (0)
#define ST_AG1(T_, C_) do {                                                    \
    STG(aS_h0g1, AsB + (C_) * 32768 +  8192 + tid * 16, T_);                   \
    STG(aS_h1g1, AsB + (C_) * 32768 + 24576 + tid * 16, T_); } while (0)
#define ST_BG0(T_, C_) do {                                                    \
    STG(bS_h0g0, BsB + (C_) * 32768 +     0 + tid * 16, T_);                   \
    STG(bS_h1g0, BsB + (C_) * 32768 + 16384 + tid * 16, T_); } while (0)
#define ST_BG1(T_, C_) do {                                                    \
    STG(bS_h0g1, BsB + (C_) * 32768 +  8192 + tid * 16, T_);                   \
    STG(bS_h1g1, BsB + (C_) * 32768 + 24576 + tid * 16, T_); } while (0)

#define RDPH_A(DST_, MI0_, C_)                                                 \
    _Pragma("unroll") for (int mi_ = 0; mi_ < 4; ++mi_)                        \
      _Pragma("unroll") for (int s_ = 0; s_ < 2; ++s_)                         \
        DST_[mi_][s_] = *(const bf16x8*)(aRd0 + (C_) * 32768 +                 \
                                         ((MI0_) + mi_) * 2048 + rds[s_]);
#define RDPH_B(DST_, NI0_, C_)                                                 \
    _Pragma("unroll") for (int ni_ = 0; ni_ < 2; ++ni_)                        \
      _Pragma("unroll") for (int s_ = 0; s_ < 2; ++s_)                         \
        DST_[ni_][s_] = *(const bf16x8*)(bRd0 + (C_) * 32768 +                 \
                                         ((NI0_) + ni_) * 2048 + rds[s_]);

#define QUAD(MI0_, NI0_, AF_, BF_)                                             \
    __builtin_amdgcn_s_setprio(1);                                             \
    _Pragma("unroll") for (int mi_ = 0; mi_ < 4; ++mi_)                        \
      _Pragma("unroll") for (int ni_ = 0; ni_ < 2; ++ni_)                      \
        _Pragma("unroll") for (int s_ = 0; s_ < 2; ++s_)                       \
          acc[(MI0_) + mi_][(NI0_) + ni_] =                                    \
            __builtin_amdgcn_mfma_f32_16x16x32_bf16(                           \
              AF_[mi_][s_], BF_[ni_][s_],                                      \
              acc[(MI0_) + mi_][(NI0_) + ni_], 0, 0, 0);                       \
    __builtin_amdgcn_s_setprio(0);

// One K-tile = 4 phases; quadrant order gives max register reuse
// (24 ds_read_b128/K-tile = byte-minimal for a 128x64 wave tile).
// Staging of tile t+2 (into the buffer being read) — region safety:
//   ph1: ST_AG0  (A rows 0-63 both halves; last read ph0, retired @ph0-end)
//   ph2: ST_BG0  (B rows 0-63; last read ph1 by wno=0 waves, retired @ph1-end)
//   ph3: ST_AG1 + ST_BG1 (A 64-127 read ph2; B 64-127 read ph1; retired)
// ONE vmcnt per K-tile at ph3-end: vmcnt(8) -> tile t+1 fully landed,
// tile t+2's 8 loads stay in flight. MODE: 1=steady, 2=drain(0), 0=none.
#define KTILE(T_, C_, MODE_) do {                                              \
    bf16x8 a03[4][2], a47[4][2], b01[2][2], b23[2][2];                         \
    /* ---- phase 0 ---- */                                                    \
    RDPH_A(a03, 0, C_);                                                        \
    RDPH_B(b01, 0, C_);                                                        \
    BARR; WAITL;                                                               \
    QUAD(0, 0, a03, b01);                                                      \
    BARR;                                                                      \
    /* ---- phase 1 ---- */                                                    \
    RDPH_B(b23, 2, C_);                                                        \
    if ((MODE_) == 1) { ST_AG0((T_) + 2, C_); }                                \
    BARR; WAITL;                                                               \
    QUAD(0, 2, a03, b23);                                                      \
    BARR;                                                                      \
    /* ---- phase 2 ---- */                                                    \
    RDPH_A(a47, 4, C_);                                                        \
    if ((MODE_) == 1) { ST_BG0((T_) + 2, C_); }                                \
    BARR; WAITL;                                                               \
    QUAD(4, 2, a47, b23);                                                      \
    BARR;                                                                      \
    /* ---- phase 3 ---- */                                                    \
    if ((MODE_) == 1) { ST_AG1((T_) + 2, C_); ST_BG1((T_) + 2, C_); }          \
    BARR;                                                                      \
    QUAD(4, 0, a47, b01);                                                      \
    if ((MODE_) == 1) { VMW(8); }                                              \
    if ((MODE_) == 2) { VMW(0); }                                              \
    BARR;                                                                      \
} while (0)

    floatx4 acc[8][4];
#pragma unroll
    for (int i = 0; i < 8; ++i)
#pragma unroll
        for (int j = 0; j < 4; ++j) acc[i][j] = 0.f;

    // Prologue: tiles 0 and 1 fully staged (16 loads). vmcnt(8): tile 0
    // landed, tile 1's 8 in flight.
    ST_AG0(0, 0); ST_BG0(0, 0); ST_AG1(0, 0); ST_BG1(0, 0);
    ST_AG0(1, 1); ST_BG0(1, 1); ST_AG1(1, 1); ST_BG1(1, 1);
    VMW(8); BARR;

    for (int t2 = 0; t2 < 15; ++t2) {        // tiles 0..29 steady-state
        KTILE(2 * t2,     0, 1);
        KTILE(2 * t2 + 1, 1, 1);
    }
    KTILE(30, 0, 2);                          // no staging; drain vmcnt(0)
    KTILE(31, 1, 0);                          // no staging, no vmcnt

#undef KTILE
#undef QUAD
#undef RDPH_A
#undef RDPH_B
#undef ST_AG0
#undef ST_AG1
#undef ST_BG0
#undef ST_BG1
#undef STG
#undef VMW
#undef WAITL
#undef BARR

    // Epilogue. C/D layout: col = lane&15, row = quad*4 + reg.
    const int wm = wmh * 128;
    const int wn = (wave & 3) * 64;
#pragma unroll
    for (int mi = 0; mi < 8; ++mi) {
#pragma unroll
        for (int r = 0; r < 4; ++r) {
            const int row = m0 + wm + mi * 16 + lq * 4 + r;
#pragma unroll
            for (int ni = 0; ni < 4; ++ni) {
                const int col = n0 + wn + ni * 16 + lr;
                float v = acc[mi][ni][r];
                if (EPI == 1) {
                    float s = v / (1.f + __expf(-v));   // silu
                    Cb[(size_t)row * DIV + col] = __float2bfloat16(s);
                } else {
                    Cf[(size_t)row * DIMV + col] = v;
                }
            }
        }
    }
}

// ---------------- scan pass 1: per-chunk carries (4 e-channels/thread) ----
__global__ __launch_bounds__(256) void scan_carry(const __hip_bfloat16* __restrict__ xp,
                                                  const float* __restrict__ logd,
                                                  const float* __restrict__ bias,
                                                  float* __restrict__ carry) {
    const int eg = blockIdx.x * 256 + threadIdx.x;  // e-group (4 channels)
    const int e0 = eg * 4;
    const int c = blockIdx.y;
    const int b = blockIdx.z;
    const float4 ld = ((const float4*)logd)[eg];
    const float4 bb = ((const float4*)bias)[eg];
    float dv[4] = {1.f / (1.f + __expf(-ld.x)), 1.f / (1.f + __expf(-ld.y)),
                   1.f / (1.f + __expf(-ld.z)), 1.f / (1.f + __expf(-ld.w))};
    float bv[4] = {bb.x, bb.y, bb.z, bb.w};
    const __hip_bfloat16* p = xp + ((size_t)(b * TV + c * CH)) * DIV + e0;
    float h[4] = {0.f, 0.f, 0.f, 0.f};
#pragma unroll 8
    for (int i = 0; i < CH; ++i) {
        bf16x4 v = *(const bf16x4*)(p + (size_t)i * DIV);
#pragma unroll
        for (int j = 0; j < 4; ++j)
            h[j] = dv[j] * ((float)v[j] + h[j]) + bv[j];
    }
    float4 o = {h[0], h[1], h[2], h[3]};
    *(float4*)&carry[((size_t)b * NCH + c) * DIV + e0] = o;
}

// ---------------- scan pass 2: combine carries, emit cell + h_final -------
__global__ __launch_bounds__(256) void scan_apply(const __hip_bfloat16* __restrict__ xp,
                                                  const float* __restrict__ logd,
                                                  const float* __restrict__ bias,
                                                  const float* __restrict__ h0,
                                                  const float* __restrict__ carry,
                                                  __hip_bfloat16* __restrict__ cell,
                                                  float* __restrict__ hfin) {
    const int eg = blockIdx.x * 256 + threadIdx.x;
    const int e0 = eg * 4;
    const int c = blockIdx.y;
    const int b = blockIdx.z;
    const float4 ld = ((const float4*)logd)[eg];
    const float4 bb = ((const float4*)bias)[eg];
    float dv[4] = {1.f / (1.f + __expf(-ld.x)), 1.f / (1.f + __expf(-ld.y)),
                   1.f / (1.f + __expf(-ld.z)), 1.f / (1.f + __expf(-ld.w))};
    float bv[4] = {bb.x, bb.y, bb.z, bb.w};
    float dCH[4];
#pragma unroll
    for (int j = 0; j < 4; ++j) dCH[j] = __powf(dv[j], (float)CH);

    // H = true h at entry to chunk c (chunk-level recurrence over carries)
    float4 H4 = *(const float4*)&h0[(size_t)b * DIV + e0];
    float H[4] = {H4.x, H4.y, H4.z, H4.w};
    for (int j = 0; j < c; ++j) {
        float4 cr = *(const float4*)&carry[((size_t)b * NCH + j) * DIV + e0];
#pragma unroll
        for (int q = 0; q < 4; ++q) H[q] = dCH[q] * H[q] + ((const float*)&cr)[q];
    }

    const size_t base = ((size_t)(b * TV + c * CH)) * DIV + e0;
    float h[4] = {H[0], H[1], H[2], H[3]};
#pragma unroll 4
    for (int i = 0; i < CH; ++i) {
        bf16x4 v = *(const bf16x4*)(xp + base + (size_t)i * DIV);
        ushort4 o;
        unsigned short* op = (unsigned short*)&o;
#pragma unroll
        for (int j = 0; j < 4; ++j) {
            h[j] = dv[j] * ((float)v[j] + h[j]) + bv[j];
            float cv = h[j] * (h[j] / (1.f + __expf(-h[j])));   // h * silu(h)
            __hip_bfloat16 cb = __float2bfloat16(cv);
            op[j] = *(unsigned short*)&cb;
        }
        *(ushort4*)(cell + base + (size_t)i * DIV) = o;
    }
    if (c == NCH - 1) {
        float4 o = {h[0], h[1], h[2], h[3]};
        *(float4*)&hfin[(size_t)b * DIV + e0] = o;
    }
}

// -------------------------------------------------------------------------
extern "C" void kernel_launch(void* const* d_in, const int* in_sizes, int n_in,
                              void* d_out, int out_size, void* d_ws, size_t ws_size,
                              hipStream_t stream) {
    const float* x     = (const float*)d_in[0];   // [B,T,DIM]
    const float* h0    = (const float*)d_in[1];   // [B,DI]
    const float* W_in  = (const float*)d_in[2];   // [DI,DIM]
    const float* W_out = (const float*)d_in[3];   // [DIM,DI]
    const float* log_d = (const float*)d_in[4];   // [DI]
    const float* bias  = (const float*)d_in[5];   // [DI]

    float* out  = (float*)d_out;                       // [B,T,DIM] fp32
    float* hfin = out + (size_t)BV * TV * DIMV;        // [B,DI] fp32

    // Workspace layout (bytes):
    char* ws = (char*)d_ws;
    __hip_bfloat16* xb    = (__hip_bfloat16*)ws;                          // 64 MiB
    __hip_bfloat16* cellb = xb;                                           // alias: x dead after GEMM1
    __hip_bfloat16* wib   = (__hip_bfloat16*)(ws + 67108864);             // 8 MiB
    __hip_bfloat16* wob   = (__hip_bfloat16*)(ws + 67108864 + 8388608);   // 8 MiB
    __hip_bfloat16* xpb   = (__hip_bfloat16*)(ws + 67108864 + 16777216);  // 64 MiB
    float*          carry = (float*)(ws + 134217728 + 16777216);          // 2 MiB

    // 1) convert inputs to bf16 (single fused kernel)
    {
        int n4 = 10485760;   // 8388608 + 1048576 + 1048576 float4s
        cvt_all<<<n4 / 256, 256, 0, stream>>>((const float4*)x, (const float4*)W_in,
                                              (const float4*)W_out,
                                              (ushort4*)xb, (ushort4*)wib, (ushort4*)wob);
    }

    // 2) GEMM1: xp = silu(x @ W_in^T), bf16 out
    gemm256_bt<1><<<dim3(DIV / 256, MV / 256), 512, 0, stream>>>(xb, wib, nullptr, xpb);

    // 3) scan: chunk carries, then combine + emit cell (bf16) and h_final
    scan_carry<<<dim3(DIV / 1024, NCH, BV), 256, 0, stream>>>(xpb, log_d, bias, carry);
    scan_apply<<<dim3(DIV / 1024, NCH, BV), 256, 0, stream>>>(xpb, log_d, bias, h0, carry, cellb, hfin);

    // 4) GEMM2: out = cell @ W_out^T, fp32 out
    gemm256_bt<0><<<dim3(DIMV / 256, MV / 256), 512, 0, stream>>>(cellb, wob, out, nullptr);
}